// Round 12
// baseline (364.149 us; speedup 1.0000x reference)
//
#include <hip/hip_runtime.h>
#include <hip/hip_bf16.h>

// HeteroGCNConv: 3-layer GCN, N=100000, E=1600000, D=128, f32.
// R11: barrier-free MFMA GEMM — A-fragments gathered DIRECTLY from global
//      (lane l reads granule A[(r0+(l&31))*128 + k0*16+(l>>5)*8], the exact
//      32x32x16 A-operand layout), no LDS, no __syncthreads, non-persistent
//      grid. Removes the stage->barrier->compute latency exposure that held
//      all three prior gemm variants at ~40us. Aggregate/build = R10.

#define D128 128
#define PBLK 256          // partition blocks; MUST equal 256 (scan-fold trick)
#define BUCKET_SHIFT 8
#define DCAP 7168         // staged edges per bucket in pass D (57KB LDS)

typedef __attribute__((ext_vector_type(8))) short s8v;     // 8 bf16 = 4 VGPR
typedef __attribute__((ext_vector_type(16))) float f16v;   // 16 f32 acc

__device__ __forceinline__ float elu1(float x) {
    return x > 0.f ? x : (expf(x) - 1.f);
}

__device__ __forceinline__ unsigned short bf16_rne(float v) {
    unsigned u = __float_as_uint(v);
    return (unsigned short)((u + 0x7fffu + ((u >> 16) & 1u)) >> 16);
}

// ---------------- build chain ----------------

__global__ __launch_bounds__(256) void part_hist2(
    const int* __restrict__ src, const int* __restrict__ dst,
    int* __restrict__ histT2, int E, int nb, int chunk, int hlen) {
    extern __shared__ int sh[];  // 2*nb ints
    for (int i = threadIdx.x; i < 2 * nb; i += 256) sh[i] = 0;
    __syncthreads();
    int b = blockIdx.x;
    int beg = b * chunk, end = min(E, beg + chunk);
    for (int e = beg + threadIdx.x; e < end; e += 256) {
        atomicAdd(&sh[dst[e] >> BUCKET_SHIFT], 1);
        atomicAdd(&sh[nb + (src[e] >> BUCKET_SHIFT)], 1);
    }
    __syncthreads();
    for (int i = threadIdx.x; i < nb; i += 256)
        histT2[i * PBLK + b] = sh[i];
    for (int i = threadIdx.x; i < nb; i += 256)
        histT2[hlen + i * PBLK + b] = sh[nb + i];
}

// In-place per-256-chunk exclusive scan; chunk sums to blockSums.
__global__ __launch_bounds__(256) void scan_block(
    int* __restrict__ data, int* __restrict__ blockSums, int n) {
    __shared__ int tmp[256];
    int gid = blockIdx.x * 256 + threadIdx.x;
    int v = (gid < n) ? data[gid] : 0;
    tmp[threadIdx.x] = v;
    __syncthreads();
    for (int off = 1; off < 256; off <<= 1) {
        int t = (threadIdx.x >= off) ? tmp[threadIdx.x - off] : 0;
        __syncthreads();
        tmp[threadIdx.x] += t;
        __syncthreads();
    }
    if (gid < n) data[gid] = tmp[threadIdx.x] - v;  // exclusive within chunk
    if (threadIdx.x == 255) blockSums[blockIdx.x] = tmp[255];
}

__global__ __launch_bounds__(1024) void scan_sums(int* __restrict__ bsums, int nb) {
    __shared__ int tmp[1024];
    int v = (threadIdx.x < nb) ? bsums[threadIdx.x] : 0;
    tmp[threadIdx.x] = v;
    __syncthreads();
    for (int off = 1; off < 1024; off <<= 1) {
        int t = (threadIdx.x >= off) ? tmp[threadIdx.x - off] : 0;
        __syncthreads();
        tmp[threadIdx.x] += t;
        __syncthreads();
    }
    if (threadIdx.x < nb) bsums[threadIdx.x] = tmp[threadIdx.x] - v;  // exclusive
}

__global__ __launch_bounds__(256) void part_scatter2(
    const int* __restrict__ src, const int* __restrict__ dst,
    const float* __restrict__ w, const int* __restrict__ offsT2,
    const int* __restrict__ bsums,
    int2* __restrict__ pkw, int2* __restrict__ skw,
    int E, int nb, int chunk, int hlen) {
    extern __shared__ int cur[];  // 2*nb ints
    int b = blockIdx.x;
    for (int i = threadIdx.x; i < nb; i += 256)
        cur[i] = offsT2[i * PBLK + b] + bsums[i];
    for (int i = threadIdx.x; i < nb; i += 256)
        cur[nb + i] = offsT2[hlen + i * PBLK + b] + bsums[nb + i] - E;
    __syncthreads();
    int beg = b * chunk, end = min(E, beg + chunk);
    for (int e = beg + threadIdx.x; e < end; e += 256) {
        int d = dst[e];
        int s = src[e];
        int wv = __float_as_int(w[e]);
        int kd = d >> BUCKET_SHIFT;
        int pos = atomicAdd(&cur[kd], 1);
        pkw[pos] = make_int2((int)((unsigned)s | ((unsigned)(d & 255) << 24)), wv);
        int ks = s >> BUCKET_SHIFT;
        int posS = atomicAdd(&cur[nb + ks], 1);
        skw[posS] = make_int2(s & 255, wv);
    }
}

__global__ __launch_bounds__(256) void bucket_sumS(
    const int2* __restrict__ skw, const int* __restrict__ offsT2,
    const int* __restrict__ bsums,
    float* __restrict__ deg_src, int E, int nb, int N, int hlen) {
    __shared__ float wsum[256];
    int k = blockIdx.x;
    int base = offsT2[hlen + k * PBLK] + bsums[nb + k] - E;
    int end = (k + 1 < nb) ? (offsT2[hlen + (k + 1) * PBLK] + bsums[nb + k + 1] - E) : E;
    int t = threadIdx.x;
    wsum[t] = 0.f;
    __syncthreads();
    for (int i = base + t; i < end; i += 256) {
        int2 v = skw[i];
        atomicAdd(&wsum[v.x], __int_as_float(v.y));
    }
    __syncthreads();
    int node = (k << BUCKET_SHIFT) + t;
    if (node < N) deg_src[node] = wsum[t];
}

// edata stores (src<<8 = byte offset into bf16 table, nw f32).
__global__ __launch_bounds__(256) void bucket_build(
    const int2* __restrict__ pkw, const int* __restrict__ offsT,
    const int* __restrict__ bsums, const float* __restrict__ deg_src,
    int* __restrict__ row_start, int2* __restrict__ edata,
    int E, int nb, int N) {
    __shared__ int cnt[256];
    __shared__ float wsum[256];
    __shared__ int loc[256];
    __shared__ int cur2[256];
    extern __shared__ int2 stage[];  // DCAP int2

    int k = blockIdx.x;
    int base = offsT[k * PBLK] + bsums[k];
    int end = (k + 1 < nb) ? (offsT[(k + 1) * PBLK] + bsums[k + 1]) : E;
    int m = end - base;
    int t = threadIdx.x;
    cnt[t] = 0;
    wsum[t] = 0.f;
    __syncthreads();
    bool staged = (m <= DCAP);
    for (int i = t; i < m; i += 256) {
        int2 kw = pkw[base + i];
        if (staged) stage[i] = kw;
        int dl = (unsigned)kw.x >> 24;
        atomicAdd(&cnt[dl], 1);
        atomicAdd(&wsum[dl], __int_as_float(kw.y));
    }
    __syncthreads();
    int v = cnt[t];
    loc[t] = v;
    __syncthreads();
    for (int off = 1; off < 256; off <<= 1) {
        int tv = (t >= off) ? loc[t - off] : 0;
        __syncthreads();
        loc[t] += tv;
        __syncthreads();
    }
    int excl = loc[t] - v;
    loc[t] = excl;
    cur2[t] = 0;
    int node = (k << BUCKET_SHIFT) + t;
    if (node < N) row_start[node] = base + excl;
    if (k == 0 && t == 0) row_start[N] = E;
    __syncthreads();
    for (int i = t; i < m; i += 256) {
        int2 kw = staged ? stage[i] : pkw[base + i];
        int dl = (unsigned)kw.x >> 24;
        int s = kw.x & 0xFFFFFF;
        int pos = base + loc[dl] + atomicAdd(&cur2[dl], 1);
        float nw = __int_as_float(kw.y) * rsqrtf(deg_src[s] * wsum[dl]);
        edata[pos] = make_int2(s << 8, __float_as_int(nw));
    }
}

// ---------------- MFMA GEMM ----------------

// W[l][k][n] f32 -> Wh/Wl bf16 in granule layout [(l*16+kc)*128+n][e], e=k&7.
__global__ __launch_bounds__(256) void prep_w(
    const float* __restrict__ W, unsigned short* __restrict__ Wh,
    unsigned short* __restrict__ Wl, int total) {
    int i = blockIdx.x * 256 + threadIdx.x;
    if (i >= total) return;
    int l = i >> 14;
    int rem = i & 16383;
    int k = rem >> 7, nn = rem & 127;
    float v = W[i];
    unsigned short h = bf16_rne(v);
    float fh = __uint_as_float((unsigned)h << 16);
    unsigned short lo = bf16_rne(v - fh);
    size_t oi = ((((size_t)l * 16 + (k >> 3)) * 128 + nn) << 3) + (k & 7);
    Wh[oi] = h;
    Wl[oi] = lo;
}

// Layer 0: A f32 -> hi/lo split in registers, 32-row tiles, no LDS/barriers.
__global__ __launch_bounds__(256) void gemm_mfma_f32(
    const float* __restrict__ A, const unsigned short* __restrict__ Wh,
    const unsigned short* __restrict__ Wl, unsigned short* __restrict__ Hb,
    int n) {
    const int t = threadIdx.x;
    const int l = t & 63;
    const int wv = t >> 6;
    const int n0 = wv * 32;
    const int lr = l & 31, lh = l >> 5;
    const int r0 = blockIdx.x * 32;

    s8v bh[8], bl[8];
#pragma unroll
    for (int k0 = 0; k0 < 8; ++k0) {
        int kc = k0 * 2 + lh;
        size_t gi = ((size_t)kc * 128 + n0 + lr) << 3;
        bh[k0] = *(const s8v*)(Wh + gi);
        bl[k0] = *(const s8v*)(Wl + gi);
    }

    int r = r0 + lr;
    if (r >= n) r = n - 1;                 // clamp; store is guarded
    const float4* pa = (const float4*)(A + (size_t)r * D128 + lh * 8);

    // Pre-load all A data (16 float4 = 64B/lane) -> MLP, then split+MFMA.
    float4 va[8][2];
#pragma unroll
    for (int k0 = 0; k0 < 8; ++k0) {
        va[k0][0] = pa[k0 * 4];
        va[k0][1] = pa[k0 * 4 + 1];
    }

    f16v acc = {0.f, 0.f, 0.f, 0.f, 0.f, 0.f, 0.f, 0.f,
                0.f, 0.f, 0.f, 0.f, 0.f, 0.f, 0.f, 0.f};
#pragma unroll
    for (int k0 = 0; k0 < 8; ++k0) {
        s8v ah, al;
#pragma unroll
        for (int e = 0; e < 8; ++e) {
            float v = (e < 4) ? ((const float*)&va[k0][0])[e]
                              : ((const float*)&va[k0][1])[e - 4];
            unsigned short h = bf16_rne(v);
            float fh = __uint_as_float((unsigned)h << 16);
            ah[e] = (short)h;
            al[e] = (short)bf16_rne(v - fh);
        }
        acc = __builtin_amdgcn_mfma_f32_32x32x16_bf16(ah, bh[k0], acc, 0, 0, 0);
        acc = __builtin_amdgcn_mfma_f32_32x32x16_bf16(ah, bl[k0], acc, 0, 0, 0);
        acc = __builtin_amdgcn_mfma_f32_32x32x16_bf16(al, bh[k0], acc, 0, 0, 0);
    }

    // D mapping: col = lane&31, row = (reg&3) + 8*(reg>>2) + 4*(lane>>5)
#pragma unroll
    for (int rg = 0; rg < 16; ++rg) {
        int grow = r0 + (rg & 3) + 8 * (rg >> 2) + 4 * lh;
        if (grow < n) Hb[(size_t)grow * D128 + n0 + lr] = bf16_rne(acc[rg]);
    }
}

// Layers 1+: A bf16 (exact), 64-row tiles, no LDS/barriers.
__global__ __launch_bounds__(256) void gemm_mfma_bf16(
    const unsigned short* __restrict__ A, const unsigned short* __restrict__ Wh,
    const unsigned short* __restrict__ Wl, unsigned short* __restrict__ Hb,
    int n) {
    const int t = threadIdx.x;
    const int l = t & 63;
    const int wv = t >> 6;
    const int n0 = wv * 32;
    const int lr = l & 31, lh = l >> 5;
    const int r0 = blockIdx.x * 64;

    s8v bh[8], bl[8];
#pragma unroll
    for (int k0 = 0; k0 < 8; ++k0) {
        int kc = k0 * 2 + lh;
        size_t gi = ((size_t)kc * 128 + n0 + lr) << 3;
        bh[k0] = *(const s8v*)(Wh + gi);
        bl[k0] = *(const s8v*)(Wl + gi);
    }

    int ra = r0 + lr;
    int rb2 = r0 + 32 + lr;
    if (ra >= n) ra = n - 1;               // clamp; stores guarded
    if (rb2 >= n) rb2 = n - 1;
    const s8v* pa0 = (const s8v*)(A + (size_t)ra * D128 + lh * 8);
    const s8v* pa1 = (const s8v*)(A + (size_t)rb2 * D128 + lh * 8);

    s8v a0[8], a1[8];
#pragma unroll
    for (int k0 = 0; k0 < 8; ++k0) {
        a0[k0] = pa0[k0 * 2];
        a1[k0] = pa1[k0 * 2];
    }

    f16v acc0 = {0.f, 0.f, 0.f, 0.f, 0.f, 0.f, 0.f, 0.f,
                 0.f, 0.f, 0.f, 0.f, 0.f, 0.f, 0.f, 0.f};
    f16v acc1 = acc0;
#pragma unroll
    for (int k0 = 0; k0 < 8; ++k0) {
        acc0 = __builtin_amdgcn_mfma_f32_32x32x16_bf16(a0[k0], bh[k0], acc0, 0, 0, 0);
        acc0 = __builtin_amdgcn_mfma_f32_32x32x16_bf16(a0[k0], bl[k0], acc0, 0, 0, 0);
        acc1 = __builtin_amdgcn_mfma_f32_32x32x16_bf16(a1[k0], bh[k0], acc1, 0, 0, 0);
        acc1 = __builtin_amdgcn_mfma_f32_32x32x16_bf16(a1[k0], bl[k0], acc1, 0, 0, 0);
    }

#pragma unroll
    for (int rg = 0; rg < 16; ++rg) {
        int rr = (rg & 3) + 8 * (rg >> 2) + 4 * lh;
        int grow0 = r0 + rr;
        int grow1 = r0 + 32 + rr;
        if (grow0 < n) Hb[(size_t)grow0 * D128 + n0 + lr] = bf16_rne(acc0[rg]);
        if (grow1 < n) Hb[(size_t)grow1 * D128 + n0 + lr] = bf16_rne(acc1[rg]);
    }
}

// ---------------- aggregate (R10) ----------------

// Two nodes per wave: lanes 0-31 -> node A, 32-63 -> node B. Within a half:
// 16 lanes x 16B chunks, 2 edge slots, x2 unroll. edata.x = src<<8.
__global__ __launch_bounds__(256) void aggregate_bf16(
    const unsigned short* __restrict__ hb, const int* __restrict__ rs,
    const int2* __restrict__ edata, const float* __restrict__ bias,
    unsigned short* __restrict__ outb, float* __restrict__ outf,
    int obf, int n) {
    int wave = threadIdx.x >> 6;
    int lane = threadIdx.x & 63;
    int node = blockIdx.x * 8 + wave * 2 + (lane >> 5);
    if (node >= n) return;
    int beg = rs[node], end = rs[node + 1];
    int eg = (lane >> 4) & 1;     // edge slot 0..1
    int c = lane & 15;            // 16B col chunk
    const char* base = (const char*)hb + c * 16;
    float a0[8] = {0.f, 0.f, 0.f, 0.f, 0.f, 0.f, 0.f, 0.f};
    float a1[8] = {0.f, 0.f, 0.f, 0.f, 0.f, 0.f, 0.f, 0.f};
    int i = beg;
    for (; i + 3 < end; i += 4) {
        int2 e0 = edata[i + eg];
        int2 e1 = edata[i + 2 + eg];
        uint4 p0 = *(const uint4*)(base + (unsigned)e0.x);
        uint4 p1 = *(const uint4*)(base + (unsigned)e1.x);
        float w0 = __int_as_float(e0.y), w1 = __int_as_float(e1.y);
#pragma unroll
        for (int j = 0; j < 4; ++j) {
            unsigned q0 = ((const unsigned*)&p0)[j];
            unsigned q1 = ((const unsigned*)&p1)[j];
            a0[2 * j]     = fmaf(__uint_as_float(q0 << 16), w0, a0[2 * j]);
            a0[2 * j + 1] = fmaf(__uint_as_float(q0 & 0xffff0000u), w0, a0[2 * j + 1]);
            a1[2 * j]     = fmaf(__uint_as_float(q1 << 16), w1, a1[2 * j]);
            a1[2 * j + 1] = fmaf(__uint_as_float(q1 & 0xffff0000u), w1, a1[2 * j + 1]);
        }
    }
    for (; i + eg < end; i += 2) {
        int2 e0 = edata[i + eg];
        uint4 p0 = *(const uint4*)(base + (unsigned)e0.x);
        float w0 = __int_as_float(e0.y);
#pragma unroll
        for (int j = 0; j < 4; ++j) {
            unsigned q0 = ((const unsigned*)&p0)[j];
            a0[2 * j]     = fmaf(__uint_as_float(q0 << 16), w0, a0[2 * j]);
            a0[2 * j + 1] = fmaf(__uint_as_float(q0 & 0xffff0000u), w0, a0[2 * j + 1]);
        }
    }
#pragma unroll
    for (int k = 0; k < 8; ++k) {
        a0[k] += a1[k];
        a0[k] += __shfl_xor(a0[k], 16);   // combine the two edge slots
    }
    if ((lane & 16) == 0) {
        float4 b0 = ((const float4*)bias)[c * 2];
        float4 b1 = ((const float4*)bias)[c * 2 + 1];
        float o[8];
        o[0] = elu1(a0[0] + b0.x);
        o[1] = elu1(a0[1] + b0.y);
        o[2] = elu1(a0[2] + b0.z);
        o[3] = elu1(a0[3] + b0.w);
        o[4] = elu1(a0[4] + b1.x);
        o[5] = elu1(a0[5] + b1.y);
        o[6] = elu1(a0[6] + b1.z);
        o[7] = elu1(a0[7] + b1.w);
        if (obf) {
            uint4 p;
            p.x = (unsigned)bf16_rne(o[0]) | ((unsigned)bf16_rne(o[1]) << 16);
            p.y = (unsigned)bf16_rne(o[2]) | ((unsigned)bf16_rne(o[3]) << 16);
            p.z = (unsigned)bf16_rne(o[4]) | ((unsigned)bf16_rne(o[5]) << 16);
            p.w = (unsigned)bf16_rne(o[6]) | ((unsigned)bf16_rne(o[7]) << 16);
            ((uint4*)(outb + (size_t)node * D128))[c] = p;
        } else {
            float4 q0 = make_float4(o[0], o[1], o[2], o[3]);
            float4 q1 = make_float4(o[4], o[5], o[6], o[7]);
            ((float4*)(outf + (size_t)node * D128))[c * 2] = q0;
            ((float4*)(outf + (size_t)node * D128))[c * 2 + 1] = q1;
        }
    }
}

extern "C" void kernel_launch(void* const* d_in, const int* in_sizes, int n_in,
                              void* d_out, int out_size, void* d_ws, size_t ws_size,
                              hipStream_t stream) {
    const float* x   = (const float*)d_in[0];
    const float* ew  = (const float*)d_in[1];
    const float* W   = (const float*)d_in[2];
    const float* b   = (const float*)d_in[3];
    const int*   src = (const int*)d_in[4];
    const int*   dst = (const int*)d_in[5];
    float* out = (float*)d_out;

    const int N = in_sizes[0] / D128;
    const int E = in_sizes[1];
    const int L = in_sizes[2] / (D128 * D128);   // == 3 here
    const int nb = (N + 255) >> BUCKET_SHIFT;
    const int hlen = nb * PBLK;

    char* ws = (char*)d_ws;
    size_t off = 0;
    auto take = [&](size_t bytes) {
        void* p = ws + off;
        off = (off + bytes + 255) & ~(size_t)255;
        return p;
    };
    float* deg_src = (float*)take((size_t)N * 4);
    int*   histT2  = (int*)take((size_t)2 * hlen * 4);  // scanned in-place
    int*   bsums   = (int*)take(1024 * 4);
    int*   rstart  = (int*)take((size_t)(N + 1) * 4);
    int2*  edata   = (int2*)take((size_t)E * 8);
    unsigned short* Hb = (unsigned short*)take((size_t)N * D128 * 2);
    unsigned short* Ab = (unsigned short*)take((size_t)N * D128 * 2);
    unsigned short* Whg = (unsigned short*)take((size_t)L * D128 * D128 * 2);
    unsigned short* Wlg = (unsigned short*)take((size_t)L * D128 * D128 * 2);
    // partition scratch aliases Ab (dead before agg0 writes Ab):
    int2* pkw = (int2*)Ab;                     // E * 8
    int2* skw = ((int2*)Ab) + E;               // E * 8

    const int chunk = (E + PBLK - 1) / PBLK;
    const int sb2 = (2 * hlen + 255) / 256;    // == 2*nb <= 1024
    const size_t part_lds = (size_t)2 * nb * 4;
    const size_t dcap_lds = (size_t)DCAP * 8;

    const int wtotal = L * D128 * D128;
    prep_w<<<(wtotal + 255) / 256, 256, 0, stream>>>(W, Whg, Wlg, wtotal);

    part_hist2<<<PBLK, 256, part_lds, stream>>>(src, dst, histT2, E, nb, chunk, hlen);
    scan_block<<<sb2, 256, 0, stream>>>(histT2, bsums, 2 * hlen);
    scan_sums<<<1, 1024, 0, stream>>>(bsums, sb2);
    part_scatter2<<<PBLK, 256, part_lds, stream>>>(src, dst, ew, histT2, bsums,
                                                   pkw, skw, E, nb, chunk, hlen);
    bucket_sumS<<<nb, 256, 0, stream>>>(skw, histT2, bsums, deg_src, E, nb, N, hlen);
    bucket_build<<<nb, 256, dcap_lds, stream>>>(pkw, histT2, bsums, deg_src,
                                                rstart, edata, E, nb, N);

    const int g32 = (N + 31) / 32;
    const int g64 = (N + 63) / 64;
    const int agg_grid = (N + 7) / 8;

    // layer 0: x(f32) --mfma--> Hb ; agg(+b0,ELU) --> Ab (bf16)
    gemm_mfma_f32<<<g32, 256, 0, stream>>>(x, Whg, Wlg, Hb, N);
    aggregate_bf16<<<agg_grid, 256, 0, stream>>>(Hb, rstart, edata, b,
                                                 Ab, nullptr, 1, N);
    // layer 1: Ab --mfma--> Hb ; agg(+b1,ELU) --> Ab
    gemm_mfma_bf16<<<g64, 256, 0, stream>>>(Ab, Whg + D128 * D128,
                                            Wlg + D128 * D128, Hb, N);
    aggregate_bf16<<<agg_grid, 256, 0, stream>>>(Hb, rstart, edata, b + D128,
                                                 Ab, nullptr, 1, N);
    // layer 2: Ab --mfma--> Hb ; agg(+b2,ELU) --> d_out (f32)
    gemm_mfma_bf16<<<g64, 256, 0, stream>>>(Ab, Whg + 2 * D128 * D128,
                                            Wlg + 2 * D128 * D128, Hb, N);
    aggregate_bf16<<<agg_grid, 256, 0, stream>>>(Hb, rstart, edata, b + 2 * D128,
                                                 nullptr, out, 0, N);
}

// Round 13
// 332.653 us; speedup vs baseline: 1.0947x; 1.0947x over previous
//
#include <hip/hip_runtime.h>
#include <hip/hip_bf16.h>

// HeteroGCNConv: 3-layer GCN, N=100000, E=1600000, D=128, f32.
// R12: restore R10 (best: 341us) — LDS-staged persistent MFMA gemms +
//      two-nodes-per-wave aggregate — with gemm grid 512->1024 (4 blocks/CU)
//      for more block-level latency overlap. R11's direct-global A-fragment
//      gather regressed (4x L1 re-read, 32 lines/instr) and is reverted.

#define D128 128
#define PBLK 256          // partition blocks; MUST equal 256 (scan-fold trick)
#define BUCKET_SHIFT 8
#define DCAP 7168         // staged edges per bucket in pass D (57KB LDS)

typedef __attribute__((ext_vector_type(8))) short s8v;     // 8 bf16 = 4 VGPR
typedef __attribute__((ext_vector_type(16))) float f16v;   // 16 f32 acc

__device__ __forceinline__ float elu1(float x) {
    return x > 0.f ? x : (expf(x) - 1.f);
}

__device__ __forceinline__ unsigned short bf16_rne(float v) {
    unsigned u = __float_as_uint(v);
    return (unsigned short)((u + 0x7fffu + ((u >> 16) & 1u)) >> 16);
}

// ---------------- build chain ----------------

__global__ __launch_bounds__(256) void part_hist2(
    const int* __restrict__ src, const int* __restrict__ dst,
    int* __restrict__ histT2, int E, int nb, int chunk, int hlen) {
    extern __shared__ int sh[];  // 2*nb ints
    for (int i = threadIdx.x; i < 2 * nb; i += 256) sh[i] = 0;
    __syncthreads();
    int b = blockIdx.x;
    int beg = b * chunk, end = min(E, beg + chunk);
    for (int e = beg + threadIdx.x; e < end; e += 256) {
        atomicAdd(&sh[dst[e] >> BUCKET_SHIFT], 1);
        atomicAdd(&sh[nb + (src[e] >> BUCKET_SHIFT)], 1);
    }
    __syncthreads();
    for (int i = threadIdx.x; i < nb; i += 256)
        histT2[i * PBLK + b] = sh[i];
    for (int i = threadIdx.x; i < nb; i += 256)
        histT2[hlen + i * PBLK + b] = sh[nb + i];
}

// In-place per-256-chunk exclusive scan; chunk sums to blockSums.
__global__ __launch_bounds__(256) void scan_block(
    int* __restrict__ data, int* __restrict__ blockSums, int n) {
    __shared__ int tmp[256];
    int gid = blockIdx.x * 256 + threadIdx.x;
    int v = (gid < n) ? data[gid] : 0;
    tmp[threadIdx.x] = v;
    __syncthreads();
    for (int off = 1; off < 256; off <<= 1) {
        int t = (threadIdx.x >= off) ? tmp[threadIdx.x - off] : 0;
        __syncthreads();
        tmp[threadIdx.x] += t;
        __syncthreads();
    }
    if (gid < n) data[gid] = tmp[threadIdx.x] - v;  // exclusive within chunk
    if (threadIdx.x == 255) blockSums[blockIdx.x] = tmp[255];
}

__global__ __launch_bounds__(1024) void scan_sums(int* __restrict__ bsums, int nb) {
    __shared__ int tmp[1024];
    int v = (threadIdx.x < nb) ? bsums[threadIdx.x] : 0;
    tmp[threadIdx.x] = v;
    __syncthreads();
    for (int off = 1; off < 1024; off <<= 1) {
        int t = (threadIdx.x >= off) ? tmp[threadIdx.x - off] : 0;
        __syncthreads();
        tmp[threadIdx.x] += t;
        __syncthreads();
    }
    if (threadIdx.x < nb) bsums[threadIdx.x] = tmp[threadIdx.x] - v;  // exclusive
}

__global__ __launch_bounds__(256) void part_scatter2(
    const int* __restrict__ src, const int* __restrict__ dst,
    const float* __restrict__ w, const int* __restrict__ offsT2,
    const int* __restrict__ bsums,
    int2* __restrict__ pkw, int2* __restrict__ skw,
    int E, int nb, int chunk, int hlen) {
    extern __shared__ int cur[];  // 2*nb ints
    int b = blockIdx.x;
    for (int i = threadIdx.x; i < nb; i += 256)
        cur[i] = offsT2[i * PBLK + b] + bsums[i];
    for (int i = threadIdx.x; i < nb; i += 256)
        cur[nb + i] = offsT2[hlen + i * PBLK + b] + bsums[nb + i] - E;
    __syncthreads();
    int beg = b * chunk, end = min(E, beg + chunk);
    for (int e = beg + threadIdx.x; e < end; e += 256) {
        int d = dst[e];
        int s = src[e];
        int wv = __float_as_int(w[e]);
        int kd = d >> BUCKET_SHIFT;
        int pos = atomicAdd(&cur[kd], 1);
        pkw[pos] = make_int2((int)((unsigned)s | ((unsigned)(d & 255) << 24)), wv);
        int ks = s >> BUCKET_SHIFT;
        int posS = atomicAdd(&cur[nb + ks], 1);
        skw[posS] = make_int2(s & 255, wv);
    }
}

__global__ __launch_bounds__(256) void bucket_sumS(
    const int2* __restrict__ skw, const int* __restrict__ offsT2,
    const int* __restrict__ bsums,
    float* __restrict__ deg_src, int E, int nb, int N, int hlen) {
    __shared__ float wsum[256];
    int k = blockIdx.x;
    int base = offsT2[hlen + k * PBLK] + bsums[nb + k] - E;
    int end = (k + 1 < nb) ? (offsT2[hlen + (k + 1) * PBLK] + bsums[nb + k + 1] - E) : E;
    int t = threadIdx.x;
    wsum[t] = 0.f;
    __syncthreads();
    for (int i = base + t; i < end; i += 256) {
        int2 v = skw[i];
        atomicAdd(&wsum[v.x], __int_as_float(v.y));
    }
    __syncthreads();
    int node = (k << BUCKET_SHIFT) + t;
    if (node < N) deg_src[node] = wsum[t];
}

// edata stores (src<<8 = byte offset into bf16 table, nw f32).
__global__ __launch_bounds__(256) void bucket_build(
    const int2* __restrict__ pkw, const int* __restrict__ offsT,
    const int* __restrict__ bsums, const float* __restrict__ deg_src,
    int* __restrict__ row_start, int2* __restrict__ edata,
    int E, int nb, int N) {
    __shared__ int cnt[256];
    __shared__ float wsum[256];
    __shared__ int loc[256];
    __shared__ int cur2[256];
    extern __shared__ int2 stage[];  // DCAP int2

    int k = blockIdx.x;
    int base = offsT[k * PBLK] + bsums[k];
    int end = (k + 1 < nb) ? (offsT[(k + 1) * PBLK] + bsums[k + 1]) : E;
    int m = end - base;
    int t = threadIdx.x;
    cnt[t] = 0;
    wsum[t] = 0.f;
    __syncthreads();
    bool staged = (m <= DCAP);
    for (int i = t; i < m; i += 256) {
        int2 kw = pkw[base + i];
        if (staged) stage[i] = kw;
        int dl = (unsigned)kw.x >> 24;
        atomicAdd(&cnt[dl], 1);
        atomicAdd(&wsum[dl], __int_as_float(kw.y));
    }
    __syncthreads();
    int v = cnt[t];
    loc[t] = v;
    __syncthreads();
    for (int off = 1; off < 256; off <<= 1) {
        int tv = (t >= off) ? loc[t - off] : 0;
        __syncthreads();
        loc[t] += tv;
        __syncthreads();
    }
    int excl = loc[t] - v;
    loc[t] = excl;
    cur2[t] = 0;
    int node = (k << BUCKET_SHIFT) + t;
    if (node < N) row_start[node] = base + excl;
    if (k == 0 && t == 0) row_start[N] = E;
    __syncthreads();
    for (int i = t; i < m; i += 256) {
        int2 kw = staged ? stage[i] : pkw[base + i];
        int dl = (unsigned)kw.x >> 24;
        int s = kw.x & 0xFFFFFF;
        int pos = base + loc[dl] + atomicAdd(&cur2[dl], 1);
        float nw = __int_as_float(kw.y) * rsqrtf(deg_src[s] * wsum[dl]);
        edata[pos] = make_int2(s << 8, __float_as_int(nw));
    }
}

// ---------------- MFMA GEMM ----------------

// W[l][k][n] f32 -> Wh/Wl bf16 in granule layout [(l*16+kc)*128+n][e], e=k&7.
__global__ __launch_bounds__(256) void prep_w(
    const float* __restrict__ W, unsigned short* __restrict__ Wh,
    unsigned short* __restrict__ Wl, int total) {
    int i = blockIdx.x * 256 + threadIdx.x;
    if (i >= total) return;
    int l = i >> 14;
    int rem = i & 16383;
    int k = rem >> 7, nn = rem & 127;
    float v = W[i];
    unsigned short h = bf16_rne(v);
    float fh = __uint_as_float((unsigned)h << 16);
    unsigned short lo = bf16_rne(v - fh);
    size_t oi = ((((size_t)l * 16 + (k >> 3)) * 128 + nn) << 3) + (k & 7);
    Wh[oi] = h;
    Wl[oi] = lo;
}

// Layer 0: A f32, hi/lo split, 32-row tiles, persistent blocks.
__global__ __launch_bounds__(256) void gemm_mfma_f32(
    const float* __restrict__ A, const unsigned short* __restrict__ Wh,
    const unsigned short* __restrict__ Wl, unsigned short* __restrict__ Hb,
    int n, int nblk) {
    __shared__ s8v lds_hi[16][32];  // [kc][row^(kc&7)]
    __shared__ s8v lds_lo[16][32];
    const int t = threadIdx.x;
    const int l = t & 63;
    const int wv = t >> 6;
    const int n0 = wv * 32;
    const int lr = l & 31, lh = l >> 5;

    s8v bh[8], bl[8];
#pragma unroll
    for (int k0 = 0; k0 < 8; ++k0) {
        int kc = k0 * 2 + lh;
        size_t gi = ((size_t)kc * 128 + n0 + lr) << 3;
        bh[k0] = *(const s8v*)(Wh + gi);
        bl[k0] = *(const s8v*)(Wl + gi);
    }

    const int row = t >> 3;
    const int kc0 = t & 7;
    for (int rb = blockIdx.x; rb < nblk; rb += gridDim.x) {
        const int r0 = rb * 32;
        __syncthreads();  // protect LDS from previous tile's readers
        {
            int r = r0 + row;
#pragma unroll
            for (int hhalf = 0; hhalf < 2; ++hhalf) {
                int kc = kc0 + 8 * hhalf;
                float4 v0 = make_float4(0.f, 0.f, 0.f, 0.f), v1 = v0;
                if (r < n) {
                    const float4* ap = (const float4*)(A + (size_t)r * D128 + kc * 8);
                    v0 = ap[0];
                    v1 = ap[1];
                }
                s8v sh, sl;
#pragma unroll
                for (int e = 0; e < 8; ++e) {
                    float v = (e < 4) ? ((const float*)&v0)[e] : ((const float*)&v1)[e - 4];
                    unsigned short h = bf16_rne(v);
                    float fh = __uint_as_float((unsigned)h << 16);
                    sh[e] = (short)h;
                    sl[e] = (short)bf16_rne(v - fh);
                }
                lds_hi[kc][row ^ (kc & 7)] = sh;
                lds_lo[kc][row ^ (kc & 7)] = sl;
            }
        }
        __syncthreads();

        f16v acc = {0.f, 0.f, 0.f, 0.f, 0.f, 0.f, 0.f, 0.f,
                    0.f, 0.f, 0.f, 0.f, 0.f, 0.f, 0.f, 0.f};
#pragma unroll
        for (int k0 = 0; k0 < 8; ++k0) {
            int kc = k0 * 2 + lh;
            s8v ah = lds_hi[kc][lr ^ (kc & 7)];
            s8v al = lds_lo[kc][lr ^ (kc & 7)];
            acc = __builtin_amdgcn_mfma_f32_32x32x16_bf16(ah, bh[k0], acc, 0, 0, 0);
            acc = __builtin_amdgcn_mfma_f32_32x32x16_bf16(ah, bl[k0], acc, 0, 0, 0);
            acc = __builtin_amdgcn_mfma_f32_32x32x16_bf16(al, bh[k0], acc, 0, 0, 0);
        }

#pragma unroll
        for (int rg = 0; rg < 16; ++rg) {
            int grow = r0 + (rg & 3) + 8 * (rg >> 2) + 4 * lh;
            if (grow < n) Hb[(size_t)grow * D128 + n0 + lr] = bf16_rne(acc[rg]);
        }
    }
}

// Layers 1+: A bf16 (exact), 64-row tiles, persistent blocks.
__global__ __launch_bounds__(256) void gemm_mfma_bf16(
    const unsigned short* __restrict__ A, const unsigned short* __restrict__ Wh,
    const unsigned short* __restrict__ Wl, unsigned short* __restrict__ Hb,
    int n, int nblk) {
    __shared__ s8v lds_a[16][64];   // [kc][row^(kc&7)]
    const int t = threadIdx.x;
    const int l = t & 63;
    const int wv = t >> 6;
    const int n0 = wv * 32;
    const int lr = l & 31, lh = l >> 5;

    s8v bh[8], bl[8];
#pragma unroll
    for (int k0 = 0; k0 < 8; ++k0) {
        int kc = k0 * 2 + lh;
        size_t gi = ((size_t)kc * 128 + n0 + lr) << 3;
        bh[k0] = *(const s8v*)(Wh + gi);
        bl[k0] = *(const s8v*)(Wl + gi);
    }

    for (int rb = blockIdx.x; rb < nblk; rb += gridDim.x) {
        const int r0 = rb * 64;
        __syncthreads();  // protect LDS from previous tile's readers
#pragma unroll
        for (int g4 = 0; g4 < 4; ++g4) {
            int g = t * 4 + g4;
            int row = g >> 4, kc = g & 15;
            int r = r0 + row;
            s8v v = {0, 0, 0, 0, 0, 0, 0, 0};
            if (r < n) v = *(const s8v*)(A + (size_t)r * D128 + kc * 8);
            lds_a[kc][row ^ (kc & 7)] = v;
        }
        __syncthreads();

        f16v acc0 = {0.f, 0.f, 0.f, 0.f, 0.f, 0.f, 0.f, 0.f,
                     0.f, 0.f, 0.f, 0.f, 0.f, 0.f, 0.f, 0.f};
        f16v acc1 = acc0;
#pragma unroll
        for (int k0 = 0; k0 < 8; ++k0) {
            int kc = k0 * 2 + lh;
            s8v a0 = lds_a[kc][lr ^ (kc & 7)];
            s8v a1 = lds_a[kc][(32 + lr) ^ (kc & 7)];
            acc0 = __builtin_amdgcn_mfma_f32_32x32x16_bf16(a0, bh[k0], acc0, 0, 0, 0);
            acc0 = __builtin_amdgcn_mfma_f32_32x32x16_bf16(a0, bl[k0], acc0, 0, 0, 0);
            acc1 = __builtin_amdgcn_mfma_f32_32x32x16_bf16(a1, bh[k0], acc1, 0, 0, 0);
            acc1 = __builtin_amdgcn_mfma_f32_32x32x16_bf16(a1, bl[k0], acc1, 0, 0, 0);
        }

#pragma unroll
        for (int rg = 0; rg < 16; ++rg) {
            int rr = (rg & 3) + 8 * (rg >> 2) + 4 * lh;
            int grow0 = r0 + rr;
            int grow1 = r0 + 32 + rr;
            if (grow0 < n) Hb[(size_t)grow0 * D128 + n0 + lr] = bf16_rne(acc0[rg]);
            if (grow1 < n) Hb[(size_t)grow1 * D128 + n0 + lr] = bf16_rne(acc1[rg]);
        }
    }
}

// ---------------- aggregate (R10) ----------------

// Two nodes per wave: lanes 0-31 -> node A, 32-63 -> node B. Within a half:
// 16 lanes x 16B chunks, 2 edge slots, x2 unroll. edata.x = src<<8.
__global__ __launch_bounds__(256) void aggregate_bf16(
    const unsigned short* __restrict__ hb, const int* __restrict__ rs,
    const int2* __restrict__ edata, const float* __restrict__ bias,
    unsigned short* __restrict__ outb, float* __restrict__ outf,
    int obf, int n) {
    int wave = threadIdx.x >> 6;
    int lane = threadIdx.x & 63;
    int node = blockIdx.x * 8 + wave * 2 + (lane >> 5);
    if (node >= n) return;
    int beg = rs[node], end = rs[node + 1];
    int eg = (lane >> 4) & 1;     // edge slot 0..1
    int c = lane & 15;            // 16B col chunk
    const char* base = (const char*)hb + c * 16;
    float a0[8] = {0.f, 0.f, 0.f, 0.f, 0.f, 0.f, 0.f, 0.f};
    float a1[8] = {0.f, 0.f, 0.f, 0.f, 0.f, 0.f, 0.f, 0.f};
    int i = beg;
    for (; i + 3 < end; i += 4) {
        int2 e0 = edata[i + eg];
        int2 e1 = edata[i + 2 + eg];
        uint4 p0 = *(const uint4*)(base + (unsigned)e0.x);
        uint4 p1 = *(const uint4*)(base + (unsigned)e1.x);
        float w0 = __int_as_float(e0.y), w1 = __int_as_float(e1.y);
#pragma unroll
        for (int j = 0; j < 4; ++j) {
            unsigned q0 = ((const unsigned*)&p0)[j];
            unsigned q1 = ((const unsigned*)&p1)[j];
            a0[2 * j]     = fmaf(__uint_as_float(q0 << 16), w0, a0[2 * j]);
            a0[2 * j + 1] = fmaf(__uint_as_float(q0 & 0xffff0000u), w0, a0[2 * j + 1]);
            a1[2 * j]     = fmaf(__uint_as_float(q1 << 16), w1, a1[2 * j]);
            a1[2 * j + 1] = fmaf(__uint_as_float(q1 & 0xffff0000u), w1, a1[2 * j + 1]);
        }
    }
    for (; i + eg < end; i += 2) {
        int2 e0 = edata[i + eg];
        uint4 p0 = *(const uint4*)(base + (unsigned)e0.x);
        float w0 = __int_as_float(e0.y);
#pragma unroll
        for (int j = 0; j < 4; ++j) {
            unsigned q0 = ((const unsigned*)&p0)[j];
            a0[2 * j]     = fmaf(__uint_as_float(q0 << 16), w0, a0[2 * j]);
            a0[2 * j + 1] = fmaf(__uint_as_float(q0 & 0xffff0000u), w0, a0[2 * j + 1]);
        }
    }
#pragma unroll
    for (int k = 0; k < 8; ++k) {
        a0[k] += a1[k];
        a0[k] += __shfl_xor(a0[k], 16);   // combine the two edge slots
    }
    if ((lane & 16) == 0) {
        float4 b0 = ((const float4*)bias)[c * 2];
        float4 b1 = ((const float4*)bias)[c * 2 + 1];
        float o[8];
        o[0] = elu1(a0[0] + b0.x);
        o[1] = elu1(a0[1] + b0.y);
        o[2] = elu1(a0[2] + b0.z);
        o[3] = elu1(a0[3] + b0.w);
        o[4] = elu1(a0[4] + b1.x);
        o[5] = elu1(a0[5] + b1.y);
        o[6] = elu1(a0[6] + b1.z);
        o[7] = elu1(a0[7] + b1.w);
        if (obf) {
            uint4 p;
            p.x = (unsigned)bf16_rne(o[0]) | ((unsigned)bf16_rne(o[1]) << 16);
            p.y = (unsigned)bf16_rne(o[2]) | ((unsigned)bf16_rne(o[3]) << 16);
            p.z = (unsigned)bf16_rne(o[4]) | ((unsigned)bf16_rne(o[5]) << 16);
            p.w = (unsigned)bf16_rne(o[6]) | ((unsigned)bf16_rne(o[7]) << 16);
            ((uint4*)(outb + (size_t)node * D128))[c] = p;
        } else {
            float4 q0 = make_float4(o[0], o[1], o[2], o[3]);
            float4 q1 = make_float4(o[4], o[5], o[6], o[7]);
            ((float4*)(outf + (size_t)node * D128))[c * 2] = q0;
            ((float4*)(outf + (size_t)node * D128))[c * 2 + 1] = q1;
        }
    }
}

extern "C" void kernel_launch(void* const* d_in, const int* in_sizes, int n_in,
                              void* d_out, int out_size, void* d_ws, size_t ws_size,
                              hipStream_t stream) {
    const float* x   = (const float*)d_in[0];
    const float* ew  = (const float*)d_in[1];
    const float* W   = (const float*)d_in[2];
    const float* b   = (const float*)d_in[3];
    const int*   src = (const int*)d_in[4];
    const int*   dst = (const int*)d_in[5];
    float* out = (float*)d_out;

    const int N = in_sizes[0] / D128;
    const int E = in_sizes[1];
    const int L = in_sizes[2] / (D128 * D128);   // == 3 here
    const int nb = (N + 255) >> BUCKET_SHIFT;
    const int hlen = nb * PBLK;

    char* ws = (char*)d_ws;
    size_t off = 0;
    auto take = [&](size_t bytes) {
        void* p = ws + off;
        off = (off + bytes + 255) & ~(size_t)255;
        return p;
    };
    float* deg_src = (float*)take((size_t)N * 4);
    int*   histT2  = (int*)take((size_t)2 * hlen * 4);  // scanned in-place
    int*   bsums   = (int*)take(1024 * 4);
    int*   rstart  = (int*)take((size_t)(N + 1) * 4);
    int2*  edata   = (int2*)take((size_t)E * 8);
    unsigned short* Hb = (unsigned short*)take((size_t)N * D128 * 2);
    unsigned short* Ab = (unsigned short*)take((size_t)N * D128 * 2);
    unsigned short* Whg = (unsigned short*)take((size_t)L * D128 * D128 * 2);
    unsigned short* Wlg = (unsigned short*)take((size_t)L * D128 * D128 * 2);
    // partition scratch aliases Ab (dead before agg0 writes Ab):
    int2* pkw = (int2*)Ab;                     // E * 8
    int2* skw = ((int2*)Ab) + E;               // E * 8

    const int chunk = (E + PBLK - 1) / PBLK;
    const int sb2 = (2 * hlen + 255) / 256;    // == 2*nb <= 1024
    const size_t part_lds = (size_t)2 * nb * 4;
    const size_t dcap_lds = (size_t)DCAP * 8;

    const int wtotal = L * D128 * D128;
    prep_w<<<(wtotal + 255) / 256, 256, 0, stream>>>(W, Whg, Wlg, wtotal);

    part_hist2<<<PBLK, 256, part_lds, stream>>>(src, dst, histT2, E, nb, chunk, hlen);
    scan_block<<<sb2, 256, 0, stream>>>(histT2, bsums, 2 * hlen);
    scan_sums<<<1, 1024, 0, stream>>>(bsums, sb2);
    part_scatter2<<<PBLK, 256, part_lds, stream>>>(src, dst, ew, histT2, bsums,
                                                   pkw, skw, E, nb, chunk, hlen);
    bucket_sumS<<<nb, 256, 0, stream>>>(skw, histT2, bsums, deg_src, E, nb, N, hlen);
    bucket_build<<<nb, 256, dcap_lds, stream>>>(pkw, histT2, bsums, deg_src,
                                                rstart, edata, E, nb, N);

    const int t32 = (N + 31) / 32;
    const int t64 = (N + 63) / 64;
    const int gemm_grid = 1024;
    const int agg_grid = (N + 7) / 8;

    // layer 0: x(f32) --mfma--> Hb ; agg(+b0,ELU) --> Ab (bf16)
    gemm_mfma_f32<<<gemm_grid, 256, 0, stream>>>(x, Whg, Wlg, Hb, N, t32);
    aggregate_bf16<<<agg_grid, 256, 0, stream>>>(Hb, rstart, edata, b,
                                                 Ab, nullptr, 1, N);
    // layer 1: Ab --mfma--> Hb ; agg(+b1,ELU) --> Ab
    gemm_mfma_bf16<<<gemm_grid, 256, 0, stream>>>(Ab, Whg + D128 * D128,
                                                  Wlg + D128 * D128, Hb, N, t64);
    aggregate_bf16<<<agg_grid, 256, 0, stream>>>(Hb, rstart, edata, b + D128,
                                                 Ab, nullptr, 1, N);
    // layer 2: Ab --mfma--> Hb ; agg(+b2,ELU) --> d_out (f32)
    gemm_mfma_bf16<<<gemm_grid, 256, 0, stream>>>(Ab, Whg + 2 * D128 * D128,
                                                  Wlg + 2 * D128 * D128, Hb, N, t64);
    aggregate_bf16<<<agg_grid, 256, 0, stream>>>(Hb, rstart, edata, b + 2 * D128,
                                                 nullptr, out, 0, N);
}

// Round 14
// 324.502 us; speedup vs baseline: 1.1222x; 1.0251x over previous
//
#include <hip/hip_runtime.h>
#include <hip/hip_bf16.h>

// HeteroGCNConv: 3-layer GCN, N=100000, E=1600000, D=128, f32.
// R13: R12 frozen (best 333us) + fat-block build chain: part_hist2/
//      part_scatter2 at 1024 thr/block (16 waves/CU vs 4), bucket_sumS/
//      bucket_build at 512 thr/block. Build kernels had 1-1.5 blocks/CU —
//      latency-exposed; hypothesis: build is the hidden ~60-80us, not gemm.

#define D128 128
#define PBLK 256          // partition blocks; MUST equal 256 (scan-fold trick)
#define BUCKET_SHIFT 8
#define DCAP 7168         // staged edges per bucket in pass D (57KB LDS)

typedef __attribute__((ext_vector_type(8))) short s8v;     // 8 bf16 = 4 VGPR
typedef __attribute__((ext_vector_type(16))) float f16v;   // 16 f32 acc

__device__ __forceinline__ float elu1(float x) {
    return x > 0.f ? x : (expf(x) - 1.f);
}

__device__ __forceinline__ unsigned short bf16_rne(float v) {
    unsigned u = __float_as_uint(v);
    return (unsigned short)((u + 0x7fffu + ((u >> 16) & 1u)) >> 16);
}

// ---------------- build chain ----------------

__global__ __launch_bounds__(1024) void part_hist2(
    const int* __restrict__ src, const int* __restrict__ dst,
    int* __restrict__ histT2, int E, int nb, int chunk, int hlen) {
    extern __shared__ int sh[];  // 2*nb ints
    for (int i = threadIdx.x; i < 2 * nb; i += 1024) sh[i] = 0;
    __syncthreads();
    int b = blockIdx.x;
    int beg = b * chunk, end = min(E, beg + chunk);
    for (int e = beg + threadIdx.x; e < end; e += 1024) {
        atomicAdd(&sh[dst[e] >> BUCKET_SHIFT], 1);
        atomicAdd(&sh[nb + (src[e] >> BUCKET_SHIFT)], 1);
    }
    __syncthreads();
    for (int i = threadIdx.x; i < nb; i += 1024)
        histT2[i * PBLK + b] = sh[i];
    for (int i = threadIdx.x; i < nb; i += 1024)
        histT2[hlen + i * PBLK + b] = sh[nb + i];
}

// In-place per-256-chunk exclusive scan; chunk sums to blockSums.
__global__ __launch_bounds__(256) void scan_block(
    int* __restrict__ data, int* __restrict__ blockSums, int n) {
    __shared__ int tmp[256];
    int gid = blockIdx.x * 256 + threadIdx.x;
    int v = (gid < n) ? data[gid] : 0;
    tmp[threadIdx.x] = v;
    __syncthreads();
    for (int off = 1; off < 256; off <<= 1) {
        int t = (threadIdx.x >= off) ? tmp[threadIdx.x - off] : 0;
        __syncthreads();
        tmp[threadIdx.x] += t;
        __syncthreads();
    }
    if (gid < n) data[gid] = tmp[threadIdx.x] - v;  // exclusive within chunk
    if (threadIdx.x == 255) blockSums[blockIdx.x] = tmp[255];
}

__global__ __launch_bounds__(1024) void scan_sums(int* __restrict__ bsums, int nb) {
    __shared__ int tmp[1024];
    int v = (threadIdx.x < nb) ? bsums[threadIdx.x] : 0;
    tmp[threadIdx.x] = v;
    __syncthreads();
    for (int off = 1; off < 1024; off <<= 1) {
        int t = (threadIdx.x >= off) ? tmp[threadIdx.x - off] : 0;
        __syncthreads();
        tmp[threadIdx.x] += t;
        __syncthreads();
    }
    if (threadIdx.x < nb) bsums[threadIdx.x] = tmp[threadIdx.x] - v;  // exclusive
}

__global__ __launch_bounds__(1024) void part_scatter2(
    const int* __restrict__ src, const int* __restrict__ dst,
    const float* __restrict__ w, const int* __restrict__ offsT2,
    const int* __restrict__ bsums,
    int2* __restrict__ pkw, int2* __restrict__ skw,
    int E, int nb, int chunk, int hlen) {
    extern __shared__ int cur[];  // 2*nb ints
    int b = blockIdx.x;
    for (int i = threadIdx.x; i < nb; i += 1024)
        cur[i] = offsT2[i * PBLK + b] + bsums[i];
    for (int i = threadIdx.x; i < nb; i += 1024)
        cur[nb + i] = offsT2[hlen + i * PBLK + b] + bsums[nb + i] - E;
    __syncthreads();
    int beg = b * chunk, end = min(E, beg + chunk);
    for (int e = beg + threadIdx.x; e < end; e += 1024) {
        int d = dst[e];
        int s = src[e];
        int wv = __float_as_int(w[e]);
        int kd = d >> BUCKET_SHIFT;
        int pos = atomicAdd(&cur[kd], 1);
        pkw[pos] = make_int2((int)((unsigned)s | ((unsigned)(d & 255) << 24)), wv);
        int ks = s >> BUCKET_SHIFT;
        int posS = atomicAdd(&cur[nb + ks], 1);
        skw[posS] = make_int2(s & 255, wv);
    }
}

__global__ __launch_bounds__(512) void bucket_sumS(
    const int2* __restrict__ skw, const int* __restrict__ offsT2,
    const int* __restrict__ bsums,
    float* __restrict__ deg_src, int E, int nb, int N, int hlen) {
    __shared__ float wsum[256];
    int k = blockIdx.x;
    int base = offsT2[hlen + k * PBLK] + bsums[nb + k] - E;
    int end = (k + 1 < nb) ? (offsT2[hlen + (k + 1) * PBLK] + bsums[nb + k + 1] - E) : E;
    int t = threadIdx.x;
    if (t < 256) wsum[t] = 0.f;
    __syncthreads();
    for (int i = base + t; i < end; i += 512) {
        int2 v = skw[i];
        atomicAdd(&wsum[v.x], __int_as_float(v.y));
    }
    __syncthreads();
    if (t < 256) {
        int node = (k << BUCKET_SHIFT) + t;
        if (node < N) deg_src[node] = wsum[t];
    }
}

// edata stores (src<<8 = byte offset into bf16 table, nw f32).
__global__ __launch_bounds__(512) void bucket_build(
    const int2* __restrict__ pkw, const int* __restrict__ offsT,
    const int* __restrict__ bsums, const float* __restrict__ deg_src,
    int* __restrict__ row_start, int2* __restrict__ edata,
    int E, int nb, int N) {
    __shared__ int cnt[256];
    __shared__ float wsum[256];
    __shared__ int loc[256];
    __shared__ int cur2[256];
    extern __shared__ int2 stage[];  // DCAP int2

    int k = blockIdx.x;
    int base = offsT[k * PBLK] + bsums[k];
    int end = (k + 1 < nb) ? (offsT[(k + 1) * PBLK] + bsums[k + 1]) : E;
    int m = end - base;
    int t = threadIdx.x;
    if (t < 256) {
        cnt[t] = 0;
        wsum[t] = 0.f;
    }
    __syncthreads();
    bool staged = (m <= DCAP);
    for (int i = t; i < m; i += 512) {
        int2 kw = pkw[base + i];
        if (staged) stage[i] = kw;
        int dl = (unsigned)kw.x >> 24;
        atomicAdd(&cnt[dl], 1);
        atomicAdd(&wsum[dl], __int_as_float(kw.y));
    }
    __syncthreads();
    int v = (t < 256) ? cnt[t] : 0;
    if (t < 256) loc[t] = v;
    __syncthreads();
    for (int off = 1; off < 256; off <<= 1) {
        int tv = (t >= off && t < 256) ? loc[t - off] : 0;
        __syncthreads();
        if (t < 256) loc[t] += tv;
        __syncthreads();
    }
    if (t < 256) {
        int excl = loc[t] - v;
        loc[t] = excl;
        cur2[t] = 0;
        int node = (k << BUCKET_SHIFT) + t;
        if (node < N) row_start[node] = base + excl;
    }
    if (k == 0 && t == 0) row_start[N] = E;
    __syncthreads();
    for (int i = t; i < m; i += 512) {
        int2 kw = staged ? stage[i] : pkw[base + i];
        int dl = (unsigned)kw.x >> 24;
        int s = kw.x & 0xFFFFFF;
        int pos = base + loc[dl] + atomicAdd(&cur2[dl], 1);
        float nw = __int_as_float(kw.y) * rsqrtf(deg_src[s] * wsum[dl]);
        edata[pos] = make_int2(s << 8, __float_as_int(nw));
    }
}

// ---------------- MFMA GEMM ----------------

// W[l][k][n] f32 -> Wh/Wl bf16 in granule layout [(l*16+kc)*128+n][e], e=k&7.
__global__ __launch_bounds__(256) void prep_w(
    const float* __restrict__ W, unsigned short* __restrict__ Wh,
    unsigned short* __restrict__ Wl, int total) {
    int i = blockIdx.x * 256 + threadIdx.x;
    if (i >= total) return;
    int l = i >> 14;
    int rem = i & 16383;
    int k = rem >> 7, nn = rem & 127;
    float v = W[i];
    unsigned short h = bf16_rne(v);
    float fh = __uint_as_float((unsigned)h << 16);
    unsigned short lo = bf16_rne(v - fh);
    size_t oi = ((((size_t)l * 16 + (k >> 3)) * 128 + nn) << 3) + (k & 7);
    Wh[oi] = h;
    Wl[oi] = lo;
}

// Layer 0: A f32, hi/lo split, 32-row tiles, persistent blocks.
__global__ __launch_bounds__(256) void gemm_mfma_f32(
    const float* __restrict__ A, const unsigned short* __restrict__ Wh,
    const unsigned short* __restrict__ Wl, unsigned short* __restrict__ Hb,
    int n, int nblk) {
    __shared__ s8v lds_hi[16][32];  // [kc][row^(kc&7)]
    __shared__ s8v lds_lo[16][32];
    const int t = threadIdx.x;
    const int l = t & 63;
    const int wv = t >> 6;
    const int n0 = wv * 32;
    const int lr = l & 31, lh = l >> 5;

    s8v bh[8], bl[8];
#pragma unroll
    for (int k0 = 0; k0 < 8; ++k0) {
        int kc = k0 * 2 + lh;
        size_t gi = ((size_t)kc * 128 + n0 + lr) << 3;
        bh[k0] = *(const s8v*)(Wh + gi);
        bl[k0] = *(const s8v*)(Wl + gi);
    }

    const int row = t >> 3;
    const int kc0 = t & 7;
    for (int rb = blockIdx.x; rb < nblk; rb += gridDim.x) {
        const int r0 = rb * 32;
        __syncthreads();  // protect LDS from previous tile's readers
        {
            int r = r0 + row;
#pragma unroll
            for (int hhalf = 0; hhalf < 2; ++hhalf) {
                int kc = kc0 + 8 * hhalf;
                float4 v0 = make_float4(0.f, 0.f, 0.f, 0.f), v1 = v0;
                if (r < n) {
                    const float4* ap = (const float4*)(A + (size_t)r * D128 + kc * 8);
                    v0 = ap[0];
                    v1 = ap[1];
                }
                s8v sh, sl;
#pragma unroll
                for (int e = 0; e < 8; ++e) {
                    float v = (e < 4) ? ((const float*)&v0)[e] : ((const float*)&v1)[e - 4];
                    unsigned short h = bf16_rne(v);
                    float fh = __uint_as_float((unsigned)h << 16);
                    sh[e] = (short)h;
                    sl[e] = (short)bf16_rne(v - fh);
                }
                lds_hi[kc][row ^ (kc & 7)] = sh;
                lds_lo[kc][row ^ (kc & 7)] = sl;
            }
        }
        __syncthreads();

        f16v acc = {0.f, 0.f, 0.f, 0.f, 0.f, 0.f, 0.f, 0.f,
                    0.f, 0.f, 0.f, 0.f, 0.f, 0.f, 0.f, 0.f};
#pragma unroll
        for (int k0 = 0; k0 < 8; ++k0) {
            int kc = k0 * 2 + lh;
            s8v ah = lds_hi[kc][lr ^ (kc & 7)];
            s8v al = lds_lo[kc][lr ^ (kc & 7)];
            acc = __builtin_amdgcn_mfma_f32_32x32x16_bf16(ah, bh[k0], acc, 0, 0, 0);
            acc = __builtin_amdgcn_mfma_f32_32x32x16_bf16(ah, bl[k0], acc, 0, 0, 0);
            acc = __builtin_amdgcn_mfma_f32_32x32x16_bf16(al, bh[k0], acc, 0, 0, 0);
        }

#pragma unroll
        for (int rg = 0; rg < 16; ++rg) {
            int grow = r0 + (rg & 3) + 8 * (rg >> 2) + 4 * lh;
            if (grow < n) Hb[(size_t)grow * D128 + n0 + lr] = bf16_rne(acc[rg]);
        }
    }
}

// Layers 1+: A bf16 (exact), 64-row tiles, persistent blocks.
__global__ __launch_bounds__(256) void gemm_mfma_bf16(
    const unsigned short* __restrict__ A, const unsigned short* __restrict__ Wh,
    const unsigned short* __restrict__ Wl, unsigned short* __restrict__ Hb,
    int n, int nblk) {
    __shared__ s8v lds_a[16][64];   // [kc][row^(kc&7)]
    const int t = threadIdx.x;
    const int l = t & 63;
    const int wv = t >> 6;
    const int n0 = wv * 32;
    const int lr = l & 31, lh = l >> 5;

    s8v bh[8], bl[8];
#pragma unroll
    for (int k0 = 0; k0 < 8; ++k0) {
        int kc = k0 * 2 + lh;
        size_t gi = ((size_t)kc * 128 + n0 + lr) << 3;
        bh[k0] = *(const s8v*)(Wh + gi);
        bl[k0] = *(const s8v*)(Wl + gi);
    }

    for (int rb = blockIdx.x; rb < nblk; rb += gridDim.x) {
        const int r0 = rb * 64;
        __syncthreads();  // protect LDS from previous tile's readers
#pragma unroll
        for (int g4 = 0; g4 < 4; ++g4) {
            int g = t * 4 + g4;
            int row = g >> 4, kc = g & 15;
            int r = r0 + row;
            s8v v = {0, 0, 0, 0, 0, 0, 0, 0};
            if (r < n) v = *(const s8v*)(A + (size_t)r * D128 + kc * 8);
            lds_a[kc][row ^ (kc & 7)] = v;
        }
        __syncthreads();

        f16v acc0 = {0.f, 0.f, 0.f, 0.f, 0.f, 0.f, 0.f, 0.f,
                     0.f, 0.f, 0.f, 0.f, 0.f, 0.f, 0.f, 0.f};
        f16v acc1 = acc0;
#pragma unroll
        for (int k0 = 0; k0 < 8; ++k0) {
            int kc = k0 * 2 + lh;
            s8v a0 = lds_a[kc][lr ^ (kc & 7)];
            s8v a1 = lds_a[kc][(32 + lr) ^ (kc & 7)];
            acc0 = __builtin_amdgcn_mfma_f32_32x32x16_bf16(a0, bh[k0], acc0, 0, 0, 0);
            acc0 = __builtin_amdgcn_mfma_f32_32x32x16_bf16(a0, bl[k0], acc0, 0, 0, 0);
            acc1 = __builtin_amdgcn_mfma_f32_32x32x16_bf16(a1, bh[k0], acc1, 0, 0, 0);
            acc1 = __builtin_amdgcn_mfma_f32_32x32x16_bf16(a1, bl[k0], acc1, 0, 0, 0);
        }

#pragma unroll
        for (int rg = 0; rg < 16; ++rg) {
            int rr = (rg & 3) + 8 * (rg >> 2) + 4 * lh;
            int grow0 = r0 + rr;
            int grow1 = r0 + 32 + rr;
            if (grow0 < n) Hb[(size_t)grow0 * D128 + n0 + lr] = bf16_rne(acc0[rg]);
            if (grow1 < n) Hb[(size_t)grow1 * D128 + n0 + lr] = bf16_rne(acc1[rg]);
        }
    }
}

// ---------------- aggregate (R10) ----------------

// Two nodes per wave: lanes 0-31 -> node A, 32-63 -> node B. Within a half:
// 16 lanes x 16B chunks, 2 edge slots, x2 unroll. edata.x = src<<8.
__global__ __launch_bounds__(256) void aggregate_bf16(
    const unsigned short* __restrict__ hb, const int* __restrict__ rs,
    const int2* __restrict__ edata, const float* __restrict__ bias,
    unsigned short* __restrict__ outb, float* __restrict__ outf,
    int obf, int n) {
    int wave = threadIdx.x >> 6;
    int lane = threadIdx.x & 63;
    int node = blockIdx.x * 8 + wave * 2 + (lane >> 5);
    if (node >= n) return;
    int beg = rs[node], end = rs[node + 1];
    int eg = (lane >> 4) & 1;     // edge slot 0..1
    int c = lane & 15;            // 16B col chunk
    const char* base = (const char*)hb + c * 16;
    float a0[8] = {0.f, 0.f, 0.f, 0.f, 0.f, 0.f, 0.f, 0.f};
    float a1[8] = {0.f, 0.f, 0.f, 0.f, 0.f, 0.f, 0.f, 0.f};
    int i = beg;
    for (; i + 3 < end; i += 4) {
        int2 e0 = edata[i + eg];
        int2 e1 = edata[i + 2 + eg];
        uint4 p0 = *(const uint4*)(base + (unsigned)e0.x);
        uint4 p1 = *(const uint4*)(base + (unsigned)e1.x);
        float w0 = __int_as_float(e0.y), w1 = __int_as_float(e1.y);
#pragma unroll
        for (int j = 0; j < 4; ++j) {
            unsigned q0 = ((const unsigned*)&p0)[j];
            unsigned q1 = ((const unsigned*)&p1)[j];
            a0[2 * j]     = fmaf(__uint_as_float(q0 << 16), w0, a0[2 * j]);
            a0[2 * j + 1] = fmaf(__uint_as_float(q0 & 0xffff0000u), w0, a0[2 * j + 1]);
            a1[2 * j]     = fmaf(__uint_as_float(q1 << 16), w1, a1[2 * j]);
            a1[2 * j + 1] = fmaf(__uint_as_float(q1 & 0xffff0000u), w1, a1[2 * j + 1]);
        }
    }
    for (; i + eg < end; i += 2) {
        int2 e0 = edata[i + eg];
        uint4 p0 = *(const uint4*)(base + (unsigned)e0.x);
        float w0 = __int_as_float(e0.y);
#pragma unroll
        for (int j = 0; j < 4; ++j) {
            unsigned q0 = ((const unsigned*)&p0)[j];
            a0[2 * j]     = fmaf(__uint_as_float(q0 << 16), w0, a0[2 * j]);
            a0[2 * j + 1] = fmaf(__uint_as_float(q0 & 0xffff0000u), w0, a0[2 * j + 1]);
        }
    }
#pragma unroll
    for (int k = 0; k < 8; ++k) {
        a0[k] += a1[k];
        a0[k] += __shfl_xor(a0[k], 16);   // combine the two edge slots
    }
    if ((lane & 16) == 0) {
        float4 b0 = ((const float4*)bias)[c * 2];
        float4 b1 = ((const float4*)bias)[c * 2 + 1];
        float o[8];
        o[0] = elu1(a0[0] + b0.x);
        o[1] = elu1(a0[1] + b0.y);
        o[2] = elu1(a0[2] + b0.z);
        o[3] = elu1(a0[3] + b0.w);
        o[4] = elu1(a0[4] + b1.x);
        o[5] = elu1(a0[5] + b1.y);
        o[6] = elu1(a0[6] + b1.z);
        o[7] = elu1(a0[7] + b1.w);
        if (obf) {
            uint4 p;
            p.x = (unsigned)bf16_rne(o[0]) | ((unsigned)bf16_rne(o[1]) << 16);
            p.y = (unsigned)bf16_rne(o[2]) | ((unsigned)bf16_rne(o[3]) << 16);
            p.z = (unsigned)bf16_rne(o[4]) | ((unsigned)bf16_rne(o[5]) << 16);
            p.w = (unsigned)bf16_rne(o[6]) | ((unsigned)bf16_rne(o[7]) << 16);
            ((uint4*)(outb + (size_t)node * D128))[c] = p;
        } else {
            float4 q0 = make_float4(o[0], o[1], o[2], o[3]);
            float4 q1 = make_float4(o[4], o[5], o[6], o[7]);
            ((float4*)(outf + (size_t)node * D128))[c * 2] = q0;
            ((float4*)(outf + (size_t)node * D128))[c * 2 + 1] = q1;
        }
    }
}

extern "C" void kernel_launch(void* const* d_in, const int* in_sizes, int n_in,
                              void* d_out, int out_size, void* d_ws, size_t ws_size,
                              hipStream_t stream) {
    const float* x   = (const float*)d_in[0];
    const float* ew  = (const float*)d_in[1];
    const float* W   = (const float*)d_in[2];
    const float* b   = (const float*)d_in[3];
    const int*   src = (const int*)d_in[4];
    const int*   dst = (const int*)d_in[5];
    float* out = (float*)d_out;

    const int N = in_sizes[0] / D128;
    const int E = in_sizes[1];
    const int L = in_sizes[2] / (D128 * D128);   // == 3 here
    const int nb = (N + 255) >> BUCKET_SHIFT;
    const int hlen = nb * PBLK;

    char* ws = (char*)d_ws;
    size_t off = 0;
    auto take = [&](size_t bytes) {
        void* p = ws + off;
        off = (off + bytes + 255) & ~(size_t)255;
        return p;
    };
    float* deg_src = (float*)take((size_t)N * 4);
    int*   histT2  = (int*)take((size_t)2 * hlen * 4);  // scanned in-place
    int*   bsums   = (int*)take(1024 * 4);
    int*   rstart  = (int*)take((size_t)(N + 1) * 4);
    int2*  edata   = (int2*)take((size_t)E * 8);
    unsigned short* Hb = (unsigned short*)take((size_t)N * D128 * 2);
    unsigned short* Ab = (unsigned short*)take((size_t)N * D128 * 2);
    unsigned short* Whg = (unsigned short*)take((size_t)L * D128 * D128 * 2);
    unsigned short* Wlg = (unsigned short*)take((size_t)L * D128 * D128 * 2);
    // partition scratch aliases Ab (dead before agg0 writes Ab):
    int2* pkw = (int2*)Ab;                     // E * 8
    int2* skw = ((int2*)Ab) + E;               // E * 8

    const int chunk = (E + PBLK - 1) / PBLK;
    const int sb2 = (2 * hlen + 255) / 256;    // == 2*nb <= 1024
    const size_t part_lds = (size_t)2 * nb * 4;
    const size_t dcap_lds = (size_t)DCAP * 8;

    const int wtotal = L * D128 * D128;
    prep_w<<<(wtotal + 255) / 256, 256, 0, stream>>>(W, Whg, Wlg, wtotal);

    part_hist2<<<PBLK, 1024, part_lds, stream>>>(src, dst, histT2, E, nb, chunk, hlen);
    scan_block<<<sb2, 256, 0, stream>>>(histT2, bsums, 2 * hlen);
    scan_sums<<<1, 1024, 0, stream>>>(bsums, sb2);
    part_scatter2<<<PBLK, 1024, part_lds, stream>>>(src, dst, ew, histT2, bsums,
                                                    pkw, skw, E, nb, chunk, hlen);
    bucket_sumS<<<nb, 512, 0, stream>>>(skw, histT2, bsums, deg_src, E, nb, N, hlen);
    bucket_build<<<nb, 512, dcap_lds, stream>>>(pkw, histT2, bsums, deg_src,
                                                rstart, edata, E, nb, N);

    const int t32 = (N + 31) / 32;
    const int t64 = (N + 63) / 64;
    const int gemm_grid = 1024;
    const int agg_grid = (N + 7) / 8;

    // layer 0: x(f32) --mfma--> Hb ; agg(+b0,ELU) --> Ab (bf16)
    gemm_mfma_f32<<<gemm_grid, 256, 0, stream>>>(x, Whg, Wlg, Hb, N, t32);
    aggregate_bf16<<<agg_grid, 256, 0, stream>>>(Hb, rstart, edata, b,
                                                 Ab, nullptr, 1, N);
    // layer 1: Ab --mfma--> Hb ; agg(+b1,ELU) --> Ab
    gemm_mfma_bf16<<<gemm_grid, 256, 0, stream>>>(Ab, Whg + D128 * D128,
                                                  Wlg + D128 * D128, Hb, N, t64);
    aggregate_bf16<<<agg_grid, 256, 0, stream>>>(Hb, rstart, edata, b + D128,
                                                 Ab, nullptr, 1, N);
    // layer 2: Ab --mfma--> Hb ; agg(+b2,ELU) --> d_out (f32)
    gemm_mfma_bf16<<<gemm_grid, 256, 0, stream>>>(Ab, Whg + 2 * D128 * D128,
                                                  Wlg + 2 * D128 * D128, Hb, N, t64);
    aggregate_bf16<<<agg_grid, 256, 0, stream>>>(Hb, rstart, edata, b + 2 * D128,
                                                 nullptr, out, 0, N);
}

// Round 15
// 315.923 us; speedup vs baseline: 1.1526x; 1.0272x over previous
//
#include <hip/hip_runtime.h>
#include <hip/hip_bf16.h>

// HeteroGCNConv: 3-layer GCN, N=100000, E=1600000, D=128, f32.
// R14: R13 frozen + aggregate edata software-pipeline — next iteration's
//      edata loads issue while current row-gathers are in flight, breaking
//      the serial edata->gather dependency (each iter was lat_e + lat_p;
//      now ~max(lat_p)). Accumulation order identical -> absmax unchanged.

#define D128 128
#define PBLK 256          // partition blocks; MUST equal 256 (scan-fold trick)
#define BUCKET_SHIFT 8
#define DCAP 7168         // staged edges per bucket in pass D (57KB LDS)

typedef __attribute__((ext_vector_type(8))) short s8v;     // 8 bf16 = 4 VGPR
typedef __attribute__((ext_vector_type(16))) float f16v;   // 16 f32 acc

__device__ __forceinline__ float elu1(float x) {
    return x > 0.f ? x : (expf(x) - 1.f);
}

__device__ __forceinline__ unsigned short bf16_rne(float v) {
    unsigned u = __float_as_uint(v);
    return (unsigned short)((u + 0x7fffu + ((u >> 16) & 1u)) >> 16);
}

// ---------------- build chain ----------------

__global__ __launch_bounds__(1024) void part_hist2(
    const int* __restrict__ src, const int* __restrict__ dst,
    int* __restrict__ histT2, int E, int nb, int chunk, int hlen) {
    extern __shared__ int sh[];  // 2*nb ints
    for (int i = threadIdx.x; i < 2 * nb; i += 1024) sh[i] = 0;
    __syncthreads();
    int b = blockIdx.x;
    int beg = b * chunk, end = min(E, beg + chunk);
    for (int e = beg + threadIdx.x; e < end; e += 1024) {
        atomicAdd(&sh[dst[e] >> BUCKET_SHIFT], 1);
        atomicAdd(&sh[nb + (src[e] >> BUCKET_SHIFT)], 1);
    }
    __syncthreads();
    for (int i = threadIdx.x; i < nb; i += 1024)
        histT2[i * PBLK + b] = sh[i];
    for (int i = threadIdx.x; i < nb; i += 1024)
        histT2[hlen + i * PBLK + b] = sh[nb + i];
}

// In-place per-256-chunk exclusive scan; chunk sums to blockSums.
__global__ __launch_bounds__(256) void scan_block(
    int* __restrict__ data, int* __restrict__ blockSums, int n) {
    __shared__ int tmp[256];
    int gid = blockIdx.x * 256 + threadIdx.x;
    int v = (gid < n) ? data[gid] : 0;
    tmp[threadIdx.x] = v;
    __syncthreads();
    for (int off = 1; off < 256; off <<= 1) {
        int t = (threadIdx.x >= off) ? tmp[threadIdx.x - off] : 0;
        __syncthreads();
        tmp[threadIdx.x] += t;
        __syncthreads();
    }
    if (gid < n) data[gid] = tmp[threadIdx.x] - v;  // exclusive within chunk
    if (threadIdx.x == 255) blockSums[blockIdx.x] = tmp[255];
}

__global__ __launch_bounds__(1024) void scan_sums(int* __restrict__ bsums, int nb) {
    __shared__ int tmp[1024];
    int v = (threadIdx.x < nb) ? bsums[threadIdx.x] : 0;
    tmp[threadIdx.x] = v;
    __syncthreads();
    for (int off = 1; off < 1024; off <<= 1) {
        int t = (threadIdx.x >= off) ? tmp[threadIdx.x - off] : 0;
        __syncthreads();
        tmp[threadIdx.x] += t;
        __syncthreads();
    }
    if (threadIdx.x < nb) bsums[threadIdx.x] = tmp[threadIdx.x] - v;  // exclusive
}

__global__ __launch_bounds__(1024) void part_scatter2(
    const int* __restrict__ src, const int* __restrict__ dst,
    const float* __restrict__ w, const int* __restrict__ offsT2,
    const int* __restrict__ bsums,
    int2* __restrict__ pkw, int2* __restrict__ skw,
    int E, int nb, int chunk, int hlen) {
    extern __shared__ int cur[];  // 2*nb ints
    int b = blockIdx.x;
    for (int i = threadIdx.x; i < nb; i += 1024)
        cur[i] = offsT2[i * PBLK + b] + bsums[i];
    for (int i = threadIdx.x; i < nb; i += 1024)
        cur[nb + i] = offsT2[hlen + i * PBLK + b] + bsums[nb + i] - E;
    __syncthreads();
    int beg = b * chunk, end = min(E, beg + chunk);
    for (int e = beg + threadIdx.x; e < end; e += 1024) {
        int d = dst[e];
        int s = src[e];
        int wv = __float_as_int(w[e]);
        int kd = d >> BUCKET_SHIFT;
        int pos = atomicAdd(&cur[kd], 1);
        pkw[pos] = make_int2((int)((unsigned)s | ((unsigned)(d & 255) << 24)), wv);
        int ks = s >> BUCKET_SHIFT;
        int posS = atomicAdd(&cur[nb + ks], 1);
        skw[posS] = make_int2(s & 255, wv);
    }
}

__global__ __launch_bounds__(512) void bucket_sumS(
    const int2* __restrict__ skw, const int* __restrict__ offsT2,
    const int* __restrict__ bsums,
    float* __restrict__ deg_src, int E, int nb, int N, int hlen) {
    __shared__ float wsum[256];
    int k = blockIdx.x;
    int base = offsT2[hlen + k * PBLK] + bsums[nb + k] - E;
    int end = (k + 1 < nb) ? (offsT2[hlen + (k + 1) * PBLK] + bsums[nb + k + 1] - E) : E;
    int t = threadIdx.x;
    if (t < 256) wsum[t] = 0.f;
    __syncthreads();
    for (int i = base + t; i < end; i += 512) {
        int2 v = skw[i];
        atomicAdd(&wsum[v.x], __int_as_float(v.y));
    }
    __syncthreads();
    if (t < 256) {
        int node = (k << BUCKET_SHIFT) + t;
        if (node < N) deg_src[node] = wsum[t];
    }
}

// edata stores (src<<8 = byte offset into bf16 table, nw f32).
__global__ __launch_bounds__(512) void bucket_build(
    const int2* __restrict__ pkw, const int* __restrict__ offsT,
    const int* __restrict__ bsums, const float* __restrict__ deg_src,
    int* __restrict__ row_start, int2* __restrict__ edata,
    int E, int nb, int N) {
    __shared__ int cnt[256];
    __shared__ float wsum[256];
    __shared__ int loc[256];
    __shared__ int cur2[256];
    extern __shared__ int2 stage[];  // DCAP int2

    int k = blockIdx.x;
    int base = offsT[k * PBLK] + bsums[k];
    int end = (k + 1 < nb) ? (offsT[(k + 1) * PBLK] + bsums[k + 1]) : E;
    int m = end - base;
    int t = threadIdx.x;
    if (t < 256) {
        cnt[t] = 0;
        wsum[t] = 0.f;
    }
    __syncthreads();
    bool staged = (m <= DCAP);
    for (int i = t; i < m; i += 512) {
        int2 kw = pkw[base + i];
        if (staged) stage[i] = kw;
        int dl = (unsigned)kw.x >> 24;
        atomicAdd(&cnt[dl], 1);
        atomicAdd(&wsum[dl], __int_as_float(kw.y));
    }
    __syncthreads();
    int v = (t < 256) ? cnt[t] : 0;
    if (t < 256) loc[t] = v;
    __syncthreads();
    for (int off = 1; off < 256; off <<= 1) {
        int tv = (t >= off && t < 256) ? loc[t - off] : 0;
        __syncthreads();
        if (t < 256) loc[t] += tv;
        __syncthreads();
    }
    if (t < 256) {
        int excl = loc[t] - v;
        loc[t] = excl;
        cur2[t] = 0;
        int node = (k << BUCKET_SHIFT) + t;
        if (node < N) row_start[node] = base + excl;
    }
    if (k == 0 && t == 0) row_start[N] = E;
    __syncthreads();
    for (int i = t; i < m; i += 512) {
        int2 kw = staged ? stage[i] : pkw[base + i];
        int dl = (unsigned)kw.x >> 24;
        int s = kw.x & 0xFFFFFF;
        int pos = base + loc[dl] + atomicAdd(&cur2[dl], 1);
        float nw = __int_as_float(kw.y) * rsqrtf(deg_src[s] * wsum[dl]);
        edata[pos] = make_int2(s << 8, __float_as_int(nw));
    }
}

// ---------------- MFMA GEMM ----------------

// W[l][k][n] f32 -> Wh/Wl bf16 in granule layout [(l*16+kc)*128+n][e], e=k&7.
__global__ __launch_bounds__(256) void prep_w(
    const float* __restrict__ W, unsigned short* __restrict__ Wh,
    unsigned short* __restrict__ Wl, int total) {
    int i = blockIdx.x * 256 + threadIdx.x;
    if (i >= total) return;
    int l = i >> 14;
    int rem = i & 16383;
    int k = rem >> 7, nn = rem & 127;
    float v = W[i];
    unsigned short h = bf16_rne(v);
    float fh = __uint_as_float((unsigned)h << 16);
    unsigned short lo = bf16_rne(v - fh);
    size_t oi = ((((size_t)l * 16 + (k >> 3)) * 128 + nn) << 3) + (k & 7);
    Wh[oi] = h;
    Wl[oi] = lo;
}

// Layer 0: A f32, hi/lo split, 32-row tiles, persistent blocks.
__global__ __launch_bounds__(256) void gemm_mfma_f32(
    const float* __restrict__ A, const unsigned short* __restrict__ Wh,
    const unsigned short* __restrict__ Wl, unsigned short* __restrict__ Hb,
    int n, int nblk) {
    __shared__ s8v lds_hi[16][32];  // [kc][row^(kc&7)]
    __shared__ s8v lds_lo[16][32];
    const int t = threadIdx.x;
    const int l = t & 63;
    const int wv = t >> 6;
    const int n0 = wv * 32;
    const int lr = l & 31, lh = l >> 5;

    s8v bh[8], bl[8];
#pragma unroll
    for (int k0 = 0; k0 < 8; ++k0) {
        int kc = k0 * 2 + lh;
        size_t gi = ((size_t)kc * 128 + n0 + lr) << 3;
        bh[k0] = *(const s8v*)(Wh + gi);
        bl[k0] = *(const s8v*)(Wl + gi);
    }

    const int row = t >> 3;
    const int kc0 = t & 7;
    for (int rb = blockIdx.x; rb < nblk; rb += gridDim.x) {
        const int r0 = rb * 32;
        __syncthreads();  // protect LDS from previous tile's readers
        {
            int r = r0 + row;
#pragma unroll
            for (int hhalf = 0; hhalf < 2; ++hhalf) {
                int kc = kc0 + 8 * hhalf;
                float4 v0 = make_float4(0.f, 0.f, 0.f, 0.f), v1 = v0;
                if (r < n) {
                    const float4* ap = (const float4*)(A + (size_t)r * D128 + kc * 8);
                    v0 = ap[0];
                    v1 = ap[1];
                }
                s8v sh, sl;
#pragma unroll
                for (int e = 0; e < 8; ++e) {
                    float v = (e < 4) ? ((const float*)&v0)[e] : ((const float*)&v1)[e - 4];
                    unsigned short h = bf16_rne(v);
                    float fh = __uint_as_float((unsigned)h << 16);
                    sh[e] = (short)h;
                    sl[e] = (short)bf16_rne(v - fh);
                }
                lds_hi[kc][row ^ (kc & 7)] = sh;
                lds_lo[kc][row ^ (kc & 7)] = sl;
            }
        }
        __syncthreads();

        f16v acc = {0.f, 0.f, 0.f, 0.f, 0.f, 0.f, 0.f, 0.f,
                    0.f, 0.f, 0.f, 0.f, 0.f, 0.f, 0.f, 0.f};
#pragma unroll
        for (int k0 = 0; k0 < 8; ++k0) {
            int kc = k0 * 2 + lh;
            s8v ah = lds_hi[kc][lr ^ (kc & 7)];
            s8v al = lds_lo[kc][lr ^ (kc & 7)];
            acc = __builtin_amdgcn_mfma_f32_32x32x16_bf16(ah, bh[k0], acc, 0, 0, 0);
            acc = __builtin_amdgcn_mfma_f32_32x32x16_bf16(ah, bl[k0], acc, 0, 0, 0);
            acc = __builtin_amdgcn_mfma_f32_32x32x16_bf16(al, bh[k0], acc, 0, 0, 0);
        }

#pragma unroll
        for (int rg = 0; rg < 16; ++rg) {
            int grow = r0 + (rg & 3) + 8 * (rg >> 2) + 4 * lh;
            if (grow < n) Hb[(size_t)grow * D128 + n0 + lr] = bf16_rne(acc[rg]);
        }
    }
}

// Layers 1+: A bf16 (exact), 64-row tiles, persistent blocks.
__global__ __launch_bounds__(256) void gemm_mfma_bf16(
    const unsigned short* __restrict__ A, const unsigned short* __restrict__ Wh,
    const unsigned short* __restrict__ Wl, unsigned short* __restrict__ Hb,
    int n, int nblk) {
    __shared__ s8v lds_a[16][64];   // [kc][row^(kc&7)]
    const int t = threadIdx.x;
    const int l = t & 63;
    const int wv = t >> 6;
    const int n0 = wv * 32;
    const int lr = l & 31, lh = l >> 5;

    s8v bh[8], bl[8];
#pragma unroll
    for (int k0 = 0; k0 < 8; ++k0) {
        int kc = k0 * 2 + lh;
        size_t gi = ((size_t)kc * 128 + n0 + lr) << 3;
        bh[k0] = *(const s8v*)(Wh + gi);
        bl[k0] = *(const s8v*)(Wl + gi);
    }

    for (int rb = blockIdx.x; rb < nblk; rb += gridDim.x) {
        const int r0 = rb * 64;
        __syncthreads();  // protect LDS from previous tile's readers
#pragma unroll
        for (int g4 = 0; g4 < 4; ++g4) {
            int g = t * 4 + g4;
            int row = g >> 4, kc = g & 15;
            int r = r0 + row;
            s8v v = {0, 0, 0, 0, 0, 0, 0, 0};
            if (r < n) v = *(const s8v*)(A + (size_t)r * D128 + kc * 8);
            lds_a[kc][row ^ (kc & 7)] = v;
        }
        __syncthreads();

        f16v acc0 = {0.f, 0.f, 0.f, 0.f, 0.f, 0.f, 0.f, 0.f,
                     0.f, 0.f, 0.f, 0.f, 0.f, 0.f, 0.f, 0.f};
        f16v acc1 = acc0;
#pragma unroll
        for (int k0 = 0; k0 < 8; ++k0) {
            int kc = k0 * 2 + lh;
            s8v a0 = lds_a[kc][lr ^ (kc & 7)];
            s8v a1 = lds_a[kc][(32 + lr) ^ (kc & 7)];
            acc0 = __builtin_amdgcn_mfma_f32_32x32x16_bf16(a0, bh[k0], acc0, 0, 0, 0);
            acc0 = __builtin_amdgcn_mfma_f32_32x32x16_bf16(a0, bl[k0], acc0, 0, 0, 0);
            acc1 = __builtin_amdgcn_mfma_f32_32x32x16_bf16(a1, bh[k0], acc1, 0, 0, 0);
            acc1 = __builtin_amdgcn_mfma_f32_32x32x16_bf16(a1, bl[k0], acc1, 0, 0, 0);
        }

#pragma unroll
        for (int rg = 0; rg < 16; ++rg) {
            int rr = (rg & 3) + 8 * (rg >> 2) + 4 * lh;
            int grow0 = r0 + rr;
            int grow1 = r0 + 32 + rr;
            if (grow0 < n) Hb[(size_t)grow0 * D128 + n0 + lr] = bf16_rne(acc0[rg]);
            if (grow1 < n) Hb[(size_t)grow1 * D128 + n0 + lr] = bf16_rne(acc1[rg]);
        }
    }
}

// ---------------- aggregate ----------------

// Two nodes per wave; per half: 16 lanes x 16B chunks, 2 edge slots, x2
// unroll. R14: edata loads for iteration i+1 are issued while iteration i's
// row-gathers are in flight (software pipeline on the dependent chain).
__global__ __launch_bounds__(256) void aggregate_bf16(
    const unsigned short* __restrict__ hb, const int* __restrict__ rs,
    const int2* __restrict__ edata, const float* __restrict__ bias,
    unsigned short* __restrict__ outb, float* __restrict__ outf,
    int obf, int n) {
    int wave = threadIdx.x >> 6;
    int lane = threadIdx.x & 63;
    int node = blockIdx.x * 8 + wave * 2 + (lane >> 5);
    if (node >= n) return;
    int beg = rs[node], end = rs[node + 1];
    int eg = (lane >> 4) & 1;     // edge slot 0..1
    int c = lane & 15;            // 16B col chunk
    const char* base = (const char*)hb + c * 16;
    float a0[8] = {0.f, 0.f, 0.f, 0.f, 0.f, 0.f, 0.f, 0.f};
    float a1[8] = {0.f, 0.f, 0.f, 0.f, 0.f, 0.f, 0.f, 0.f};
    int i = beg;
    int2 e0, e1;
    bool have = (i + 3 < end);
    if (have) {
        e0 = edata[i + eg];
        e1 = edata[i + 2 + eg];
    }
    while (have) {
        uint4 p0 = *(const uint4*)(base + (unsigned)e0.x);
        uint4 p1 = *(const uint4*)(base + (unsigned)e1.x);
        float w0 = __int_as_float(e0.y), w1 = __int_as_float(e1.y);
        int ni = i + 4;
        bool more = (ni + 3 < end);
        if (more) {                       // prefetch next iter's edata now;
            e0 = edata[ni + eg];          // stays in flight across the p-wait
            e1 = edata[ni + 2 + eg];
        }
#pragma unroll
        for (int j = 0; j < 4; ++j) {
            unsigned q0 = ((const unsigned*)&p0)[j];
            unsigned q1 = ((const unsigned*)&p1)[j];
            a0[2 * j]     = fmaf(__uint_as_float(q0 << 16), w0, a0[2 * j]);
            a0[2 * j + 1] = fmaf(__uint_as_float(q0 & 0xffff0000u), w0, a0[2 * j + 1]);
            a1[2 * j]     = fmaf(__uint_as_float(q1 << 16), w1, a1[2 * j]);
            a1[2 * j + 1] = fmaf(__uint_as_float(q1 & 0xffff0000u), w1, a1[2 * j + 1]);
        }
        i = ni;
        have = more;
    }
    for (; i + eg < end; i += 2) {
        int2 et = edata[i + eg];
        uint4 p0 = *(const uint4*)(base + (unsigned)et.x);
        float w0 = __int_as_float(et.y);
#pragma unroll
        for (int j = 0; j < 4; ++j) {
            unsigned q0 = ((const unsigned*)&p0)[j];
            a0[2 * j]     = fmaf(__uint_as_float(q0 << 16), w0, a0[2 * j]);
            a0[2 * j + 1] = fmaf(__uint_as_float(q0 & 0xffff0000u), w0, a0[2 * j + 1]);
        }
    }
#pragma unroll
    for (int k = 0; k < 8; ++k) {
        a0[k] += a1[k];
        a0[k] += __shfl_xor(a0[k], 16);   // combine the two edge slots
    }
    if ((lane & 16) == 0) {
        float4 b0 = ((const float4*)bias)[c * 2];
        float4 b1 = ((const float4*)bias)[c * 2 + 1];
        float o[8];
        o[0] = elu1(a0[0] + b0.x);
        o[1] = elu1(a0[1] + b0.y);
        o[2] = elu1(a0[2] + b0.z);
        o[3] = elu1(a0[3] + b0.w);
        o[4] = elu1(a0[4] + b1.x);
        o[5] = elu1(a0[5] + b1.y);
        o[6] = elu1(a0[6] + b1.z);
        o[7] = elu1(a0[7] + b1.w);
        if (obf) {
            uint4 p;
            p.x = (unsigned)bf16_rne(o[0]) | ((unsigned)bf16_rne(o[1]) << 16);
            p.y = (unsigned)bf16_rne(o[2]) | ((unsigned)bf16_rne(o[3]) << 16);
            p.z = (unsigned)bf16_rne(o[4]) | ((unsigned)bf16_rne(o[5]) << 16);
            p.w = (unsigned)bf16_rne(o[6]) | ((unsigned)bf16_rne(o[7]) << 16);
            ((uint4*)(outb + (size_t)node * D128))[c] = p;
        } else {
            float4 q0 = make_float4(o[0], o[1], o[2], o[3]);
            float4 q1 = make_float4(o[4], o[5], o[6], o[7]);
            ((float4*)(outf + (size_t)node * D128))[c * 2] = q0;
            ((float4*)(outf + (size_t)node * D128))[c * 2 + 1] = q1;
        }
    }
}

extern "C" void kernel_launch(void* const* d_in, const int* in_sizes, int n_in,
                              void* d_out, int out_size, void* d_ws, size_t ws_size,
                              hipStream_t stream) {
    const float* x   = (const float*)d_in[0];
    const float* ew  = (const float*)d_in[1];
    const float* W   = (const float*)d_in[2];
    const float* b   = (const float*)d_in[3];
    const int*   src = (const int*)d_in[4];
    const int*   dst = (const int*)d_in[5];
    float* out = (float*)d_out;

    const int N = in_sizes[0] / D128;
    const int E = in_sizes[1];
    const int L = in_sizes[2] / (D128 * D128);   // == 3 here
    const int nb = (N + 255) >> BUCKET_SHIFT;
    const int hlen = nb * PBLK;

    char* ws = (char*)d_ws;
    size_t off = 0;
    auto take = [&](size_t bytes) {
        void* p = ws + off;
        off = (off + bytes + 255) & ~(size_t)255;
        return p;
    };
    float* deg_src = (float*)take((size_t)N * 4);
    int*   histT2  = (int*)take((size_t)2 * hlen * 4);  // scanned in-place
    int*   bsums   = (int*)take(1024 * 4);
    int*   rstart  = (int*)take((size_t)(N + 1) * 4);
    int2*  edata   = (int2*)take((size_t)E * 8);
    unsigned short* Hb = (unsigned short*)take((size_t)N * D128 * 2);
    unsigned short* Ab = (unsigned short*)take((size_t)N * D128 * 2);
    unsigned short* Whg = (unsigned short*)take((size_t)L * D128 * D128 * 2);
    unsigned short* Wlg = (unsigned short*)take((size_t)L * D128 * D128 * 2);
    // partition scratch aliases Ab (dead before agg0 writes Ab):
    int2* pkw = (int2*)Ab;                     // E * 8
    int2* skw = ((int2*)Ab) + E;               // E * 8

    const int chunk = (E + PBLK - 1) / PBLK;
    const int sb2 = (2 * hlen + 255) / 256;    // == 2*nb <= 1024
    const size_t part_lds = (size_t)2 * nb * 4;
    const size_t dcap_lds = (size_t)DCAP * 8;

    const int wtotal = L * D128 * D128;
    prep_w<<<(wtotal + 255) / 256, 256, 0, stream>>>(W, Whg, Wlg, wtotal);

    part_hist2<<<PBLK, 1024, part_lds, stream>>>(src, dst, histT2, E, nb, chunk, hlen);
    scan_block<<<sb2, 256, 0, stream>>>(histT2, bsums, 2 * hlen);
    scan_sums<<<1, 1024, 0, stream>>>(bsums, sb2);
    part_scatter2<<<PBLK, 1024, part_lds, stream>>>(src, dst, ew, histT2, bsums,
                                                    pkw, skw, E, nb, chunk, hlen);
    bucket_sumS<<<nb, 512, 0, stream>>>(skw, histT2, bsums, deg_src, E, nb, N, hlen);
    bucket_build<<<nb, 512, dcap_lds, stream>>>(pkw, histT2, bsums, deg_src,
                                                rstart, edata, E, nb, N);

    const int t32 = (N + 31) / 32;
    const int t64 = (N + 63) / 64;
    const int gemm_grid = 1024;
    const int agg_grid = (N + 7) / 8;

    // layer 0: x(f32) --mfma--> Hb ; agg(+b0,ELU) --> Ab (bf16)
    gemm_mfma_f32<<<gemm_grid, 256, 0, stream>>>(x, Whg, Wlg, Hb, N, t32);
    aggregate_bf16<<<agg_grid, 256, 0, stream>>>(Hb, rstart, edata, b,
                                                 Ab, nullptr, 1, N);
    // layer 1: Ab --mfma--> Hb ; agg(+b1,ELU) --> Ab
    gemm_mfma_bf16<<<gemm_grid, 256, 0, stream>>>(Ab, Whg + D128 * D128,
                                                  Wlg + D128 * D128, Hb, N, t64);
    aggregate_bf16<<<agg_grid, 256, 0, stream>>>(Hb, rstart, edata, b + D128,
                                                 Ab, nullptr, 1, N);
    // layer 2: Ab --mfma--> Hb ; agg(+b2,ELU) --> d_out (f32)
    gemm_mfma_bf16<<<gemm_grid, 256, 0, stream>>>(Ab, Whg + 2 * D128 * D128,
                                                  Wlg + 2 * D128 * D128, Hb, N, t64);
    aggregate_bf16<<<agg_grid, 256, 0, stream>>>(Hb, rstart, edata, b + 2 * D128,
                                                 nullptr, out, 0, N);
}